// Round 3
// baseline (266.584 us; speedup 1.0000x reference)
//
#include <hip/hip_runtime.h>

// Ontomap: loss = sum((n2f@n_e - f_e)^2) + sum((m2f@m_e - f_e)^2)
// B = 1,048,576 samples, D = 64.
// Round 3: split the two projections across block parity so each block holds
// only one B matrix (32 regs) + one accumulator pair (32 AGPRs) -> total
// ~117 regs -> 4 waves/EU (16 waves/CU), 2x the latency hiding of round 2.

typedef _Float16 half8 __attribute__((ext_vector_type(8)));
typedef __fp16  fp16x2 __attribute__((ext_vector_type(2)));
typedef float floatx16 __attribute__((ext_vector_type(16)));

#define NBLOCKS 2048            // even: n2f loss, odd: m2f loss
#define SAMPLES_PER_BLOCK 128   // 4 waves * 32 samples (per projection)

__device__ inline half8 cvt8(float4 a, float4 b) {
    union { half8 h; fp16x2 h2[4]; } u;
    u.h2[0] = __builtin_amdgcn_cvt_pkrtz(a.x, a.y);
    u.h2[1] = __builtin_amdgcn_cvt_pkrtz(a.z, a.w);
    u.h2[2] = __builtin_amdgcn_cvt_pkrtz(b.x, b.y);
    u.h2[3] = __builtin_amdgcn_cvt_pkrtz(b.z, b.w);
    return u.h;
}

__global__ __launch_bounds__(256, 4) void ontomap_kernel(
    const int* __restrict__ pos_n, const int* __restrict__ pos_m,
    const int* __restrict__ pos_f,
    const float* __restrict__ nci, const float* __restrict__ fma_emb,
    const float* __restrict__ n2f, const float* __restrict__ m2f,
    float* __restrict__ out, int iters)
{
    const int lane = threadIdx.x & 63;
    const int wave = threadIdx.x >> 6;
    const int l31  = lane & 31;
    const int hi   = lane >> 5;     // 0 or 1
    const int kbase = hi * 8;       // k offset within a 16-wide K step

    // Parity split: even blocks do n2f projection, odd blocks m2f.
    const int half  = blockIdx.x & 1;
    const int sblk  = blockIdx.x >> 1;               // 0..1023
    const int* __restrict__ pos_e = half ? pos_m : pos_n;
    const float* __restrict__ M   = half ? m2f : n2f;

    // ---- Preload B fragments for this block's projection matrix.
    // B[k][n] = M[n][k]; lane holds n = nt*32 + l31, k = t*16 + hi*8 + j.
    half8 Bx[2][4];
#pragma unroll
    for (int nt = 0; nt < 2; ++nt) {
#pragma unroll
        for (int t = 0; t < 4; ++t) {
            const float* p = M + (nt * 32 + l31) * 64 + t * 16 + kbase;
            Bx[nt][t] = cvt8(*(const float4*)p, *(const float4*)(p + 4));
        }
    }

    float loss = 0.0f;

    // Prefetch indices for iteration 0 (lanes 32-63 load duplicates of 0-31).
    int ie_, if_;
    {
        int s = sblk * SAMPLES_PER_BLOCK + wave * 32 + l31;
        ie_ = pos_e[s]; if_ = pos_f[s];
    }

#pragma unroll 1
    for (int it = 0; it < iters; ++it) {
        const int ie0 = ie_, if0 = if_;
        if (it + 1 < iters) {
            int s = ((it + 1) * (NBLOCKS / 2) + sblk) * SAMPLES_PER_BLOCK
                    + wave * 32 + l31;
            ie_ = pos_e[s]; if_ = pos_f[s];
        }

        // A gather in fragment layout: sample m = l31, k = t*16 + hi*8 + j.
        const float* pe = nci + (long)ie0 * 64 + kbase;

        floatx16 aX0{}, aX1{};
#pragma unroll
        for (int t = 0; t < 4; ++t) {
            half8 aF = cvt8(*(const float4*)(pe + t * 16),
                            *(const float4*)(pe + t * 16 + 4));
            aX0 = __builtin_amdgcn_mfma_f32_32x32x16_f16(aF, Bx[0][t], aX0, 0, 0, 0);
            aX1 = __builtin_amdgcn_mfma_f32_32x32x16_f16(aF, Bx[1][t], aX1, 0, 0, 0);
        }

        // Loss phase: C/D layout col = l31 (tile0: dims 0-31) / 32+l31 (tile1),
        // row(sample-in-group) = (r&3) + 8*(r>>2) + 4*hi.
#pragma unroll
        for (int r = 0; r < 16; ++r) {
            const int mrow = (r & 3) + 8 * (r >> 2) + 4 * hi;
            const int fid  = __shfl(if0, mrow, 64);  // lane mrow (<32) holds pos_f[base+mrow]
            const float* pf = fma_emb + (long)fid * 64 + l31;
            const float f0 = pf[0];    // dims 0..31
            const float f1 = pf[32];   // dims 32..63
            float d;
            d = aX0[r] - f0; loss = fmaf(d, d, loss);
            d = aX1[r] - f1; loss = fmaf(d, d, loss);
        }
    }

    // Wave reduction, then one atomic per wave.
#pragma unroll
    for (int o = 32; o > 0; o >>= 1) loss += __shfl_xor(loss, o, 64);
    if (lane == 0) atomicAdd(out, loss);
}

extern "C" void kernel_launch(void* const* d_in, const int* in_sizes, int n_in,
                              void* d_out, int out_size, void* d_ws, size_t ws_size,
                              hipStream_t stream) {
    const int*   pos_n   = (const int*)d_in[0];
    const int*   pos_m   = (const int*)d_in[1];
    const int*   pos_f   = (const int*)d_in[2];
    const float* nci_emb = (const float*)d_in[3];
    const float* fma_emb = (const float*)d_in[4];
    const float* n2f_mat = (const float*)d_in[5];
    const float* m2f_mat = (const float*)d_in[6];
    float* out = (float*)d_out;

    const int B = in_sizes[0];
    const int iters = B / ((NBLOCKS / 2) * SAMPLES_PER_BLOCK);  // 1,048,576 -> 8

    (void)hipMemsetAsync(out, 0, sizeof(float), stream);
    ontomap_kernel<<<NBLOCKS, 256, 0, stream>>>(
        pos_n, pos_m, pos_f, nci_emb, fma_emb, n2f_mat, m2f_mat, out, iters);
}

// Round 4
// 219.960 us; speedup vs baseline: 1.2120x; 1.2120x over previous
//
#include <hip/hip_runtime.h>

// Ontomap: loss = sum((n2f@n_e - f_e)^2) + sum((m2f@m_e - f_e)^2)
// B = 1,048,576, D = 64.
// Round 4: back to round-2 shape (both projections per block, f_e read once),
// but nci gathers are fully-coalesced (16 lanes x float4 = one 256B row,
// each 64B line touched exactly once -> 4 txns/sample instead of 8),
// converted to f16 and staged in per-wave LDS (no __syncthreads needed),
// A-fragments read back as one ds_read_b128 per K-step.

typedef _Float16 half8 __attribute__((ext_vector_type(8)));
typedef __fp16  fp16x2 __attribute__((ext_vector_type(2)));
typedef float floatx16 __attribute__((ext_vector_type(16)));

#define NBLOCKS 1024
#define SAMPLES_PER_BLOCK 128   // 4 waves * 32 samples
#define ROW_BYTES 144           // 64 f16 (128 B) + 16 B pad (breaks bank aliasing)

__device__ inline half8 cvt8(float4 a, float4 b) {
    union { half8 h; fp16x2 h2[4]; } u;
    u.h2[0] = __builtin_amdgcn_cvt_pkrtz(a.x, a.y);
    u.h2[1] = __builtin_amdgcn_cvt_pkrtz(a.z, a.w);
    u.h2[2] = __builtin_amdgcn_cvt_pkrtz(b.x, b.y);
    u.h2[3] = __builtin_amdgcn_cvt_pkrtz(b.z, b.w);
    return u.h;
}

__device__ inline void stage4(const float4 v, void* dst) {
    union { fp16x2 h2[2]; uint2 u; } p;
    p.h2[0] = __builtin_amdgcn_cvt_pkrtz(v.x, v.y);
    p.h2[1] = __builtin_amdgcn_cvt_pkrtz(v.z, v.w);
    *(uint2*)dst = p.u;
}

__global__ __launch_bounds__(256, 2) void ontomap_kernel(
    const int* __restrict__ pos_n, const int* __restrict__ pos_m,
    const int* __restrict__ pos_f,
    const float* __restrict__ nci, const float* __restrict__ fma_emb,
    const float* __restrict__ n2f, const float* __restrict__ m2f,
    float* __restrict__ out, int iters)
{
    __shared__ char lds[4 * 2 * 32 * ROW_BYTES];   // 36864 B, per-wave regions

    const int lane = threadIdx.x & 63;
    const int wave = threadIdx.x >> 6;
    const int l31  = lane & 31;
    const int hi   = lane >> 5;     // 0 or 1
    const int kbase = hi * 8;       // k offset within a 16-wide K step

    const int srow   = lane >> 4;   // 0..3: row within a group of 4
    const int schunk = lane & 15;   // float4 chunk within a 256B row

    char* const nbase = lds + wave * (2 * 32 * ROW_BYTES);
    char* const mbase = nbase + 32 * ROW_BYTES;

    // ---- Preload B fragments for both projection matrices.
    // B[k][n] = M[n][k]; lane holds n = nt*32 + l31, k = t*16 + hi*8 + j.
    half8 Bn[2][4], Bm[2][4];
#pragma unroll
    for (int nt = 0; nt < 2; ++nt) {
#pragma unroll
        for (int t = 0; t < 4; ++t) {
            const float* p = n2f + (nt * 32 + l31) * 64 + t * 16 + kbase;
            Bn[nt][t] = cvt8(*(const float4*)p, *(const float4*)(p + 4));
            const float* q = m2f + (nt * 32 + l31) * 64 + t * 16 + kbase;
            Bm[nt][t] = cvt8(*(const float4*)q, *(const float4*)(q + 4));
        }
    }

    float loss = 0.0f;

    // Prefetch indices for iteration 0 (lanes 32-63 hold duplicates of 0-31).
    int in_, im_, if_;
    {
        int s = blockIdx.x * SAMPLES_PER_BLOCK + wave * 32 + l31;
        in_ = pos_n[s]; im_ = pos_m[s]; if_ = pos_f[s];
    }

#pragma unroll 1
    for (int it = 0; it < iters; ++it) {
        const int in0 = in_, im0 = im_, if0 = if_;
        if (it + 1 < iters) {
            int s = ((it + 1) * NBLOCKS + blockIdx.x) * SAMPLES_PER_BLOCK
                    + wave * 32 + l31;
            in_ = pos_n[s]; im_ = pos_m[s]; if_ = pos_f[s];
        }

        // ---- Stage 32 n-rows + 32 m-rows into this wave's LDS region.
        // Each inst: 4 rows x 16 lanes x 16B = each 64B line touched once.
#pragma unroll
        for (int i = 0; i < 8; ++i) {
            const int rl = i * 4 + srow;
            const int rn = __shfl(in0, rl, 64);
            float4 v = ((const float4*)(nci + (long)rn * 64))[schunk];
            stage4(v, nbase + rl * ROW_BYTES + schunk * 8);
            const int rm = __shfl(im0, rl, 64);
            float4 w = ((const float4*)(nci + (long)rm * 64))[schunk];
            stage4(w, mbase + rl * ROW_BYTES + schunk * 8);
        }
        // Wave-local LDS: in-order per wave; just stop the compiler reordering.
        asm volatile("" ::: "memory");

        // ---- A-fragment reads + MFMA. lane l: sample l31, k = t*16+hi*8+j.
        floatx16 aN0{}, aN1{}, aM0{}, aM1{};
#pragma unroll
        for (int t = 0; t < 4; ++t) {
            half8 aF = *(const half8*)(nbase + l31 * ROW_BYTES + t * 32 + hi * 16);
            aN0 = __builtin_amdgcn_mfma_f32_32x32x16_f16(aF, Bn[0][t], aN0, 0, 0, 0);
            aN1 = __builtin_amdgcn_mfma_f32_32x32x16_f16(aF, Bn[1][t], aN1, 0, 0, 0);
            half8 bF = *(const half8*)(mbase + l31 * ROW_BYTES + t * 32 + hi * 16);
            aM0 = __builtin_amdgcn_mfma_f32_32x32x16_f16(bF, Bm[0][t], aM0, 0, 0, 0);
            aM1 = __builtin_amdgcn_mfma_f32_32x32x16_f16(bF, Bm[1][t], aM1, 0, 0, 0);
        }

        // ---- Loss phase: C/D layout col = l31 (tile0) / 32+l31 (tile1),
        // row(sample-in-group) = (r&3) + 8*(r>>2) + 4*hi.
#pragma unroll
        for (int r = 0; r < 16; ++r) {
            const int mrow = (r & 3) + 8 * (r >> 2) + 4 * hi;
            const int fid  = __shfl(if0, mrow, 64);
            const float* pf = fma_emb + (long)fid * 64 + l31;
            const float f0 = pf[0];    // dims 0..31
            const float f1 = pf[32];   // dims 32..63
            float d;
            d = aN0[r] - f0; loss = fmaf(d, d, loss);
            d = aM0[r] - f0; loss = fmaf(d, d, loss);
            d = aN1[r] - f1; loss = fmaf(d, d, loss);
            d = aM1[r] - f1; loss = fmaf(d, d, loss);
        }
    }

    // Wave reduction, then one atomic per wave.
#pragma unroll
    for (int o = 32; o > 0; o >>= 1) loss += __shfl_xor(loss, o, 64);
    if (lane == 0) atomicAdd(out, loss);
}

extern "C" void kernel_launch(void* const* d_in, const int* in_sizes, int n_in,
                              void* d_out, int out_size, void* d_ws, size_t ws_size,
                              hipStream_t stream) {
    const int*   pos_n   = (const int*)d_in[0];
    const int*   pos_m   = (const int*)d_in[1];
    const int*   pos_f   = (const int*)d_in[2];
    const float* nci_emb = (const float*)d_in[3];
    const float* fma_emb = (const float*)d_in[4];
    const float* n2f_mat = (const float*)d_in[5];
    const float* m2f_mat = (const float*)d_in[6];
    float* out = (float*)d_out;

    const int B = in_sizes[0];
    const int iters = B / (NBLOCKS * SAMPLES_PER_BLOCK);  // 1,048,576 -> 8

    (void)hipMemsetAsync(out, 0, sizeof(float), stream);
    ontomap_kernel<<<NBLOCKS, 256, 0, stream>>>(
        pos_n, pos_m, pos_f, nci_emb, fma_emb, n2f_mat, m2f_mat, out, iters);
}

// Round 5
// 204.620 us; speedup vs baseline: 1.3028x; 1.0750x over previous
//
#include <hip/hip_runtime.h>
#include <hip/hip_fp16.h>

// Ontomap: loss = sum((n2f@n_e - f_e)^2) + sum((m2f@m_e - f_e)^2)
// B = 1,048,576, D = 64.
// Round 5: every launch, convert both embedding tables to fp16 in d_ws
// (streaming, ~16us), then run the gather+MFMA kernel against fp16 rows
// (128 B = 2 cache lines/row instead of 4). R2-R4 showed duration ==
// FETCH_SIZE / ~2.9 TB/s (L2-miss line-rate ceiling, invariant to occupancy
// and txn shape), so halving bytes/row should halve the main kernel time.
// Falls back to the fp32-table kernel if ws_size < 32 MB.

typedef _Float16 half8 __attribute__((ext_vector_type(8)));
typedef __fp16  fp16x2 __attribute__((ext_vector_type(2)));
typedef float floatx16 __attribute__((ext_vector_type(16)));

#define NBLOCKS 1024
#define SAMPLES_PER_BLOCK 128   // 4 waves * 32 samples
#define ROW_BYTES 144           // 64 f16 (128 B) + 16 B pad
#define NCI_ELEMS 9600000       // 150000 * 64
#define FMA_ELEMS 6400000       // 100000 * 64

__device__ inline half8 cvt8(float4 a, float4 b) {
    union { half8 h; fp16x2 h2[4]; } u;
    u.h2[0] = __builtin_amdgcn_cvt_pkrtz(a.x, a.y);
    u.h2[1] = __builtin_amdgcn_cvt_pkrtz(a.z, a.w);
    u.h2[2] = __builtin_amdgcn_cvt_pkrtz(b.x, b.y);
    u.h2[3] = __builtin_amdgcn_cvt_pkrtz(b.z, b.w);
    return u.h;
}

__device__ inline uint2 pack4(float4 v) {
    union { fp16x2 h2[2]; uint2 u; } p;
    p.h2[0] = __builtin_amdgcn_cvt_pkrtz(v.x, v.y);
    p.h2[1] = __builtin_amdgcn_cvt_pkrtz(v.z, v.w);
    return p.u;
}

// ---- streaming fp32 -> fp16 table conversion into workspace.
__global__ __launch_bounds__(256) void convert_kernel(
    const float4* __restrict__ nci, const float4* __restrict__ fma,
    uint2* __restrict__ nci_h, uint2* __restrict__ fma_h)
{
    const int stride = gridDim.x * blockDim.x;
    const int tid = blockIdx.x * blockDim.x + threadIdx.x;
    for (int i = tid; i < NCI_ELEMS / 4; i += stride)
        nci_h[i] = pack4(nci[i]);
    for (int i = tid; i < FMA_ELEMS / 4; i += stride)
        fma_h[i] = pack4(fma[i]);
}

// ---- main kernel, fp16 tables.
__global__ __launch_bounds__(256, 2) void ontomap_kernel_h(
    const int* __restrict__ pos_n, const int* __restrict__ pos_m,
    const int* __restrict__ pos_f,
    const __half* __restrict__ nci, const __half* __restrict__ fma_emb,
    const float* __restrict__ n2f, const float* __restrict__ m2f,
    float* __restrict__ out, int iters)
{
    __shared__ char lds[4 * 2 * 32 * ROW_BYTES];   // 36864 B, per-wave regions

    const int lane = threadIdx.x & 63;
    const int wave = threadIdx.x >> 6;
    const int l31  = lane & 31;
    const int hi   = lane >> 5;
    const int kbase = hi * 8;

    const int srow   = lane >> 3;   // 0..7: row within a group of 8
    const int schunk = lane & 7;    // 16B chunk within a 128B fp16 row

    char* const nbase = lds + wave * (2 * 32 * ROW_BYTES);
    char* const mbase = nbase + 32 * ROW_BYTES;

    // B fragments: B[k][n] = M[n][k]; lane holds n = nt*32+l31, k = t*16+hi*8+j.
    half8 Bn[2][4], Bm[2][4];
#pragma unroll
    for (int nt = 0; nt < 2; ++nt) {
#pragma unroll
        for (int t = 0; t < 4; ++t) {
            const float* p = n2f + (nt * 32 + l31) * 64 + t * 16 + kbase;
            Bn[nt][t] = cvt8(*(const float4*)p, *(const float4*)(p + 4));
            const float* q = m2f + (nt * 32 + l31) * 64 + t * 16 + kbase;
            Bm[nt][t] = cvt8(*(const float4*)q, *(const float4*)(q + 4));
        }
    }

    float loss = 0.0f;

    int in_, im_, if_;
    {
        int s = blockIdx.x * SAMPLES_PER_BLOCK + wave * 32 + l31;
        in_ = pos_n[s]; im_ = pos_m[s]; if_ = pos_f[s];
    }

#pragma unroll 1
    for (int it = 0; it < iters; ++it) {
        const int in0 = in_, im0 = im_, if0 = if_;
        if (it + 1 < iters) {
            int s = ((it + 1) * NBLOCKS + blockIdx.x) * SAMPLES_PER_BLOCK
                    + wave * 32 + l31;
            in_ = pos_n[s]; im_ = pos_m[s]; if_ = pos_f[s];
        }

        // Stage 32 n-rows + 32 m-rows (fp16, 128 B each; 8 lanes x 16B per
        // row -> each 64B line touched exactly once).
#pragma unroll
        for (int i = 0; i < 4; ++i) {
            const int rl = i * 8 + srow;
            const int rn = __shfl(in0, rl, 64);
            uint4 v = ((const uint4*)(nci + (long)rn * 64))[schunk];
            *(uint4*)(nbase + rl * ROW_BYTES + schunk * 16) = v;
            const int rm = __shfl(im0, rl, 64);
            uint4 w = ((const uint4*)(nci + (long)rm * 64))[schunk];
            *(uint4*)(mbase + rl * ROW_BYTES + schunk * 16) = w;
        }
        asm volatile("" ::: "memory");   // wave-local LDS: order only

        // A-fragments + MFMA: lane l: sample l31, k = t*16 + hi*8 + j.
        floatx16 aN0{}, aN1{}, aM0{}, aM1{};
#pragma unroll
        for (int t = 0; t < 4; ++t) {
            half8 aF = *(const half8*)(nbase + l31 * ROW_BYTES + t * 32 + hi * 16);
            aN0 = __builtin_amdgcn_mfma_f32_32x32x16_f16(aF, Bn[0][t], aN0, 0, 0, 0);
            aN1 = __builtin_amdgcn_mfma_f32_32x32x16_f16(aF, Bn[1][t], aN1, 0, 0, 0);
            half8 bF = *(const half8*)(mbase + l31 * ROW_BYTES + t * 32 + hi * 16);
            aM0 = __builtin_amdgcn_mfma_f32_32x32x16_f16(bF, Bm[0][t], aM0, 0, 0, 0);
            aM1 = __builtin_amdgcn_mfma_f32_32x32x16_f16(bF, Bm[1][t], aM1, 0, 0, 0);
        }

        // Loss: C/D layout col = l31 / 32+l31, row = (r&3)+8*(r>>2)+4*hi.
#pragma unroll
        for (int r = 0; r < 16; ++r) {
            const int mrow = (r & 3) + 8 * (r >> 2) + 4 * hi;
            const int fid  = __shfl(if0, mrow, 64);
            const __half* pf = fma_emb + (long)fid * 64 + l31;
            const float f0 = __half2float(pf[0]);
            const float f1 = __half2float(pf[32]);
            float d;
            d = aN0[r] - f0; loss = fmaf(d, d, loss);
            d = aM0[r] - f0; loss = fmaf(d, d, loss);
            d = aN1[r] - f1; loss = fmaf(d, d, loss);
            d = aM1[r] - f1; loss = fmaf(d, d, loss);
        }
    }

#pragma unroll
    for (int o = 32; o > 0; o >>= 1) loss += __shfl_xor(loss, o, 64);
    if (lane == 0) atomicAdd(out, loss);
}

// ---- fallback: fp32 tables (round-4 kernel), used only if ws too small.
__global__ __launch_bounds__(256, 2) void ontomap_kernel_f32(
    const int* __restrict__ pos_n, const int* __restrict__ pos_m,
    const int* __restrict__ pos_f,
    const float* __restrict__ nci, const float* __restrict__ fma_emb,
    const float* __restrict__ n2f, const float* __restrict__ m2f,
    float* __restrict__ out, int iters)
{
    __shared__ char lds[4 * 2 * 32 * ROW_BYTES];

    const int lane = threadIdx.x & 63;
    const int wave = threadIdx.x >> 6;
    const int l31  = lane & 31;
    const int hi   = lane >> 5;
    const int kbase = hi * 8;
    const int srow   = lane >> 4;
    const int schunk = lane & 15;

    char* const nbase = lds + wave * (2 * 32 * ROW_BYTES);
    char* const mbase = nbase + 32 * ROW_BYTES;

    half8 Bn[2][4], Bm[2][4];
#pragma unroll
    for (int nt = 0; nt < 2; ++nt) {
#pragma unroll
        for (int t = 0; t < 4; ++t) {
            const float* p = n2f + (nt * 32 + l31) * 64 + t * 16 + kbase;
            Bn[nt][t] = cvt8(*(const float4*)p, *(const float4*)(p + 4));
            const float* q = m2f + (nt * 32 + l31) * 64 + t * 16 + kbase;
            Bm[nt][t] = cvt8(*(const float4*)q, *(const float4*)(q + 4));
        }
    }

    float loss = 0.0f;
    int in_, im_, if_;
    {
        int s = blockIdx.x * SAMPLES_PER_BLOCK + wave * 32 + l31;
        in_ = pos_n[s]; im_ = pos_m[s]; if_ = pos_f[s];
    }

#pragma unroll 1
    for (int it = 0; it < iters; ++it) {
        const int in0 = in_, im0 = im_, if0 = if_;
        if (it + 1 < iters) {
            int s = ((it + 1) * NBLOCKS + blockIdx.x) * SAMPLES_PER_BLOCK
                    + wave * 32 + l31;
            in_ = pos_n[s]; im_ = pos_m[s]; if_ = pos_f[s];
        }

        const float* dummy;
#pragma unroll
        for (int i = 0; i < 8; ++i) {
            const int rl = i * 4 + srow;
            const int rn = __shfl(in0, rl, 64);
            float4 v = ((const float4*)(nci + (long)rn * 64))[schunk];
            union { fp16x2 h2[2]; uint2 u; } pv;
            pv.h2[0] = __builtin_amdgcn_cvt_pkrtz(v.x, v.y);
            pv.h2[1] = __builtin_amdgcn_cvt_pkrtz(v.z, v.w);
            *(uint2*)(nbase + rl * ROW_BYTES + schunk * 8) = pv.u;
            const int rm = __shfl(im0, rl, 64);
            float4 w = ((const float4*)(nci + (long)rm * 64))[schunk];
            union { fp16x2 h2[2]; uint2 u; } pw;
            pw.h2[0] = __builtin_amdgcn_cvt_pkrtz(w.x, w.y);
            pw.h2[1] = __builtin_amdgcn_cvt_pkrtz(w.z, w.w);
            *(uint2*)(mbase + rl * ROW_BYTES + schunk * 8) = pw.u;
        }
        (void)dummy;
        asm volatile("" ::: "memory");

        floatx16 aN0{}, aN1{}, aM0{}, aM1{};
#pragma unroll
        for (int t = 0; t < 4; ++t) {
            half8 aF = *(const half8*)(nbase + l31 * ROW_BYTES + t * 32 + hi * 16);
            aN0 = __builtin_amdgcn_mfma_f32_32x32x16_f16(aF, Bn[0][t], aN0, 0, 0, 0);
            aN1 = __builtin_amdgcn_mfma_f32_32x32x16_f16(aF, Bn[1][t], aN1, 0, 0, 0);
            half8 bF = *(const half8*)(mbase + l31 * ROW_BYTES + t * 32 + hi * 16);
            aM0 = __builtin_amdgcn_mfma_f32_32x32x16_f16(bF, Bm[0][t], aM0, 0, 0, 0);
            aM1 = __builtin_amdgcn_mfma_f32_32x32x16_f16(bF, Bm[1][t], aM1, 0, 0, 0);
        }

#pragma unroll
        for (int r = 0; r < 16; ++r) {
            const int mrow = (r & 3) + 8 * (r >> 2) + 4 * hi;
            const int fid  = __shfl(if0, mrow, 64);
            const float* pf = fma_emb + (long)fid * 64 + l31;
            const float f0 = pf[0];
            const float f1 = pf[32];
            float d;
            d = aN0[r] - f0; loss = fmaf(d, d, loss);
            d = aM0[r] - f0; loss = fmaf(d, d, loss);
            d = aN1[r] - f1; loss = fmaf(d, d, loss);
            d = aM1[r] - f1; loss = fmaf(d, d, loss);
        }
    }

#pragma unroll
    for (int o = 32; o > 0; o >>= 1) loss += __shfl_xor(loss, o, 64);
    if (lane == 0) atomicAdd(out, loss);
}

extern "C" void kernel_launch(void* const* d_in, const int* in_sizes, int n_in,
                              void* d_out, int out_size, void* d_ws, size_t ws_size,
                              hipStream_t stream) {
    const int*   pos_n   = (const int*)d_in[0];
    const int*   pos_m   = (const int*)d_in[1];
    const int*   pos_f   = (const int*)d_in[2];
    const float* nci_emb = (const float*)d_in[3];
    const float* fma_emb = (const float*)d_in[4];
    const float* n2f_mat = (const float*)d_in[5];
    const float* m2f_mat = (const float*)d_in[6];
    float* out = (float*)d_out;

    const int B = in_sizes[0];
    const int iters = B / (NBLOCKS * SAMPLES_PER_BLOCK);  // 1,048,576 -> 8

    (void)hipMemsetAsync(out, 0, sizeof(float), stream);

    const size_t need = (size_t)(NCI_ELEMS + FMA_ELEMS) * sizeof(__half);
    if (ws_size >= need) {
        __half* nci_h = (__half*)d_ws;
        __half* fma_h = nci_h + NCI_ELEMS;
        convert_kernel<<<1024, 256, 0, stream>>>(
            (const float4*)nci_emb, (const float4*)fma_emb,
            (uint2*)nci_h, (uint2*)fma_h);
        ontomap_kernel_h<<<NBLOCKS, 256, 0, stream>>>(
            pos_n, pos_m, pos_f, nci_h, fma_h, n2f_mat, m2f_mat, out, iters);
    } else {
        ontomap_kernel_f32<<<NBLOCKS, 256, 0, stream>>>(
            pos_n, pos_m, pos_f, nci_emb, fma_emb, n2f_mat, m2f_mat, out, iters);
    }
}

// Round 6
// 197.541 us; speedup vs baseline: 1.3495x; 1.0358x over previous
//
#include <hip/hip_runtime.h>
#include <hip/hip_fp16.h>

// Ontomap: loss = sum((n2f@n_e - f_e)^2) + sum((m2f@m_e - f_e)^2)
// B = 1,048,576, D = 64.
// Round 6: (a) fp16 tables in d_ws (halved gather bytes, round 5);
// (b) f_e fused into the MFMA as [e|f] @ [M^T; -I]  -> loss phase is pure
//     register squares, killing the second memory-latency phase per iter;
// (c) staging via global_load_lds (async DMA, no VGPR round-trip, 12 insts
//     in flight per iter) with XOR-swizzled 16B chunks so unpadded 128B rows
//     don't alias LDS banks on the ds_read_b128 fragment reads.

typedef _Float16 half8 __attribute__((ext_vector_type(8)));
typedef __fp16  fp16x2 __attribute__((ext_vector_type(2)));
typedef float floatx16 __attribute__((ext_vector_type(16)));

#define NBLOCKS 1024
#define SAMPLES_PER_BLOCK 128   // 4 waves * 32 samples
#define NCI_ELEMS 9600000       // 150000 * 64
#define FMA_ELEMS 6400000       // 100000 * 64

__device__ inline half8 cvt8(float4 a, float4 b) {
    union { half8 h; fp16x2 h2[4]; } u;
    u.h2[0] = __builtin_amdgcn_cvt_pkrtz(a.x, a.y);
    u.h2[1] = __builtin_amdgcn_cvt_pkrtz(a.z, a.w);
    u.h2[2] = __builtin_amdgcn_cvt_pkrtz(b.x, b.y);
    u.h2[3] = __builtin_amdgcn_cvt_pkrtz(b.z, b.w);
    return u.h;
}

__device__ inline uint2 pack4(float4 v) {
    union { fp16x2 h2[2]; uint2 u; } p;
    p.h2[0] = __builtin_amdgcn_cvt_pkrtz(v.x, v.y);
    p.h2[1] = __builtin_amdgcn_cvt_pkrtz(v.z, v.w);
    return p.u;
}

// ---- streaming fp32 -> fp16 table conversion into workspace.
__global__ __launch_bounds__(256) void convert_kernel(
    const float4* __restrict__ nci, const float4* __restrict__ fma,
    uint2* __restrict__ nci_h, uint2* __restrict__ fma_h)
{
    const int stride = gridDim.x * blockDim.x;
    const int tid = blockIdx.x * blockDim.x + threadIdx.x;
    for (int i = tid; i < NCI_ELEMS / 4; i += stride)
        nci_h[i] = pack4(nci[i]);
    for (int i = tid; i < FMA_ELEMS / 4; i += stride)
        fma_h[i] = pack4(fma[i]);
}

// ---- main kernel: fp16 tables, DMA staging, fused f subtraction.
__global__ __launch_bounds__(256, 2) void ontomap_kernel_h(
    const int* __restrict__ pos_n, const int* __restrict__ pos_m,
    const int* __restrict__ pos_f,
    const __half* __restrict__ nci, const __half* __restrict__ fma_emb,
    const float* __restrict__ n2f, const float* __restrict__ m2f,
    float* __restrict__ out, int iters)
{
    // Per-wave regions: 3 tables x 32 rows x 128 B (no pad: DMA lands
    // lane*16 contiguous; bank aliasing handled by chunk XOR swizzle).
    __shared__ char lds[4 * 3 * 32 * 128];   // 49152 B

    const int lane = threadIdx.x & 63;
    const int wave = threadIdx.x >> 6;
    const int l31  = lane & 31;
    const int hi   = lane >> 5;
    const int kbase = hi * 8;

    const int srow8 = lane >> 3;                 // 0..7: row within group of 8
    const int swc   = (lane & 7) ^ srow8;        // swizzled 16B chunk to fetch

    char* const wb = lds + wave * (3 * 32 * 128);
    char* const nL = wb;
    char* const mL = wb + 4096;
    char* const fL = wb + 8192;

    // B fragments: B[k][n] = M[n][k]; lane holds n = nt*32+l31, k = t*16+hi*8+j.
    half8 Bn[2][4], Bm[2][4];
#pragma unroll
    for (int nt = 0; nt < 2; ++nt) {
#pragma unroll
        for (int t = 0; t < 4; ++t) {
            const float* p = n2f + (nt * 32 + l31) * 64 + t * 16 + kbase;
            Bn[nt][t] = cvt8(*(const float4*)p, *(const float4*)(p + 4));
            const float* q = m2f + (nt * 32 + l31) * 64 + t * 16 + kbase;
            Bm[nt][t] = cvt8(*(const float4*)q, *(const float4*)(q + 4));
        }
    }

    // -I fragments for the fused f subtraction. For k-step t' (f-dim
    // k' = t'*16 + hi*8 + j) and tile nt = t'>>1 (n = nt*32 + l31):
    // element = -(k' == n). Other (t',nt) combos are all-zero -> skipped.
    half8 If[4];
#pragma unroll
    for (int tp = 0; tp < 4; ++tp) {
        const int n = (tp >> 1) * 32 + l31;
#pragma unroll
        for (int j = 0; j < 8; ++j) {
            const int kp = tp * 16 + hi * 8 + j;
            If[tp][j] = (kp == n) ? (_Float16)(-1.0f) : (_Float16)(0.0f);
        }
    }

    float loss = 0.0f;

    int in_, im_, if_;
    {
        int s = blockIdx.x * SAMPLES_PER_BLOCK + wave * 32 + l31;
        in_ = pos_n[s]; im_ = pos_m[s]; if_ = pos_f[s];
    }

#pragma unroll 1
    for (int it = 0; it < iters; ++it) {
        const int in0 = in_, im0 = im_, if0 = if_;
        if (it + 1 < iters) {
            int s = ((it + 1) * NBLOCKS + blockIdx.x) * SAMPLES_PER_BLOCK
                    + wave * 32 + l31;
            in_ = pos_n[s]; im_ = pos_m[s]; if_ = pos_f[s];
        }

        // ---- 12 async DMA stages: 32 rows per table, 8 rows per inst.
        // Lane l -> row (i*8 + l>>3), global chunk swc = (l&7)^(l>>3&7),
        // lands at LDS base + lane*16 (row-major 128 B rows, swizzled chunks).
#pragma unroll
        for (int i = 0; i < 4; ++i) {
            const int rn = __shfl(in0, i * 8 + srow8, 64);
            __builtin_amdgcn_global_load_lds(
                (const __attribute__((address_space(1))) void*)(nci + (long)rn * 64 + swc * 8),
                (__attribute__((address_space(3))) void*)(nL + i * 1024), 16, 0, 0);
            const int rm = __shfl(im0, i * 8 + srow8, 64);
            __builtin_amdgcn_global_load_lds(
                (const __attribute__((address_space(1))) void*)(nci + (long)rm * 64 + swc * 8),
                (__attribute__((address_space(3))) void*)(mL + i * 1024), 16, 0, 0);
            const int rf = __shfl(if0, i * 8 + srow8, 64);
            __builtin_amdgcn_global_load_lds(
                (const __attribute__((address_space(1))) void*)(fma_emb + (long)rf * 64 + swc * 8),
                (__attribute__((address_space(3))) void*)(fL + i * 1024), 16, 0, 0);
        }
        asm volatile("s_waitcnt vmcnt(0)" ::: "memory");

        // ---- fragments + MFMA. A-frag: sample l31, k = t*16 + hi*8 + j;
        // chunk index 2t+hi, stored at position (2t+hi)^(l31&7).
        floatx16 aN0{}, aN1{}, aM0{}, aM1{};
#pragma unroll
        for (int t = 0; t < 4; ++t) {
            const int off = l31 * 128 + (((2 * t + hi) ^ (l31 & 7)) * 16);
            half8 aFn = *(const half8*)(nL + off);
            aN0 = __builtin_amdgcn_mfma_f32_32x32x16_f16(aFn, Bn[0][t], aN0, 0, 0, 0);
            aN1 = __builtin_amdgcn_mfma_f32_32x32x16_f16(aFn, Bn[1][t], aN1, 0, 0, 0);
            half8 aFm = *(const half8*)(mL + off);
            aM0 = __builtin_amdgcn_mfma_f32_32x32x16_f16(aFm, Bm[0][t], aM0, 0, 0, 0);
            aM1 = __builtin_amdgcn_mfma_f32_32x32x16_f16(aFm, Bm[1][t], aM1, 0, 0, 0);
        }
        // Fused -f: same f A-fragments feed both losses' accumulators.
#pragma unroll
        for (int tp = 0; tp < 4; ++tp) {
            const int off = l31 * 128 + (((2 * tp + hi) ^ (l31 & 7)) * 16);
            half8 fF = *(const half8*)(fL + off);
            if (tp < 2) {
                aN0 = __builtin_amdgcn_mfma_f32_32x32x16_f16(fF, If[tp], aN0, 0, 0, 0);
                aM0 = __builtin_amdgcn_mfma_f32_32x32x16_f16(fF, If[tp], aM0, 0, 0, 0);
            } else {
                aN1 = __builtin_amdgcn_mfma_f32_32x32x16_f16(fF, If[tp], aN1, 0, 0, 0);
                aM1 = __builtin_amdgcn_mfma_f32_32x32x16_f16(fF, If[tp], aM1, 0, 0, 0);
            }
        }

        // ---- loss: pure register squares (each (sample,dim) once per tile).
#pragma unroll
        for (int r = 0; r < 16; ++r) {
            loss = fmaf(aN0[r], aN0[r], loss);
            loss = fmaf(aN1[r], aN1[r], loss);
            loss = fmaf(aM0[r], aM0[r], loss);
            loss = fmaf(aM1[r], aM1[r], loss);
        }
    }

#pragma unroll
    for (int o = 32; o > 0; o >>= 1) loss += __shfl_xor(loss, o, 64);
    if (lane == 0) atomicAdd(out, loss);
}

// ---- fallback: fp32 tables (round-4/5 kernel), used only if ws too small.
#define ROW_BYTES 144
__global__ __launch_bounds__(256, 2) void ontomap_kernel_f32(
    const int* __restrict__ pos_n, const int* __restrict__ pos_m,
    const int* __restrict__ pos_f,
    const float* __restrict__ nci, const float* __restrict__ fma_emb,
    const float* __restrict__ n2f, const float* __restrict__ m2f,
    float* __restrict__ out, int iters)
{
    __shared__ char lds[4 * 2 * 32 * ROW_BYTES];

    const int lane = threadIdx.x & 63;
    const int wave = threadIdx.x >> 6;
    const int l31  = lane & 31;
    const int hi   = lane >> 5;
    const int kbase = hi * 8;
    const int srow   = lane >> 4;
    const int schunk = lane & 15;

    char* const nbase = lds + wave * (2 * 32 * ROW_BYTES);
    char* const mbase = nbase + 32 * ROW_BYTES;

    half8 Bn[2][4], Bm[2][4];
#pragma unroll
    for (int nt = 0; nt < 2; ++nt) {
#pragma unroll
        for (int t = 0; t < 4; ++t) {
            const float* p = n2f + (nt * 32 + l31) * 64 + t * 16 + kbase;
            Bn[nt][t] = cvt8(*(const float4*)p, *(const float4*)(p + 4));
            const float* q = m2f + (nt * 32 + l31) * 64 + t * 16 + kbase;
            Bm[nt][t] = cvt8(*(const float4*)q, *(const float4*)(q + 4));
        }
    }

    float loss = 0.0f;
    int in_, im_, if_;
    {
        int s = blockIdx.x * SAMPLES_PER_BLOCK + wave * 32 + l31;
        in_ = pos_n[s]; im_ = pos_m[s]; if_ = pos_f[s];
    }

#pragma unroll 1
    for (int it = 0; it < iters; ++it) {
        const int in0 = in_, im0 = im_, if0 = if_;
        if (it + 1 < iters) {
            int s = ((it + 1) * NBLOCKS + blockIdx.x) * SAMPLES_PER_BLOCK
                    + wave * 32 + l31;
            in_ = pos_n[s]; im_ = pos_m[s]; if_ = pos_f[s];
        }

#pragma unroll
        for (int i = 0; i < 8; ++i) {
            const int rl = i * 4 + srow;
            const int rn = __shfl(in0, rl, 64);
            float4 v = ((const float4*)(nci + (long)rn * 64))[schunk];
            *(uint2*)(nbase + rl * ROW_BYTES + schunk * 8) = pack4(v);
            const int rm = __shfl(im0, rl, 64);
            float4 w = ((const float4*)(nci + (long)rm * 64))[schunk];
            *(uint2*)(mbase + rl * ROW_BYTES + schunk * 8) = pack4(w);
        }
        asm volatile("" ::: "memory");

        floatx16 aN0{}, aN1{}, aM0{}, aM1{};
#pragma unroll
        for (int t = 0; t < 4; ++t) {
            half8 aF = *(const half8*)(nbase + l31 * ROW_BYTES + t * 32 + hi * 16);
            aN0 = __builtin_amdgcn_mfma_f32_32x32x16_f16(aF, Bn[0][t], aN0, 0, 0, 0);
            aN1 = __builtin_amdgcn_mfma_f32_32x32x16_f16(aF, Bn[1][t], aN1, 0, 0, 0);
            half8 bF = *(const half8*)(mbase + l31 * ROW_BYTES + t * 32 + hi * 16);
            aM0 = __builtin_amdgcn_mfma_f32_32x32x16_f16(bF, Bm[0][t], aM0, 0, 0, 0);
            aM1 = __builtin_amdgcn_mfma_f32_32x32x16_f16(bF, Bm[1][t], aM1, 0, 0, 0);
        }

#pragma unroll
        for (int r = 0; r < 16; ++r) {
            const int mrow = (r & 3) + 8 * (r >> 2) + 4 * hi;
            const int fid  = __shfl(if0, mrow, 64);
            const float* pf = fma_emb + (long)fid * 64 + l31;
            const float f0 = pf[0];
            const float f1 = pf[32];
            float d;
            d = aN0[r] - f0; loss = fmaf(d, d, loss);
            d = aM0[r] - f0; loss = fmaf(d, d, loss);
            d = aN1[r] - f1; loss = fmaf(d, d, loss);
            d = aM1[r] - f1; loss = fmaf(d, d, loss);
        }
    }

#pragma unroll
    for (int o = 32; o > 0; o >>= 1) loss += __shfl_xor(loss, o, 64);
    if (lane == 0) atomicAdd(out, loss);
}

extern "C" void kernel_launch(void* const* d_in, const int* in_sizes, int n_in,
                              void* d_out, int out_size, void* d_ws, size_t ws_size,
                              hipStream_t stream) {
    const int*   pos_n   = (const int*)d_in[0];
    const int*   pos_m   = (const int*)d_in[1];
    const int*   pos_f   = (const int*)d_in[2];
    const float* nci_emb = (const float*)d_in[3];
    const float* fma_emb = (const float*)d_in[4];
    const float* n2f_mat = (const float*)d_in[5];
    const float* m2f_mat = (const float*)d_in[6];
    float* out = (float*)d_out;

    const int B = in_sizes[0];
    const int iters = B / (NBLOCKS * SAMPLES_PER_BLOCK);  // 1,048,576 -> 8

    (void)hipMemsetAsync(out, 0, sizeof(float), stream);

    const size_t need = (size_t)(NCI_ELEMS + FMA_ELEMS) * sizeof(__half);
    if (ws_size >= need) {
        __half* nci_h = (__half*)d_ws;
        __half* fma_h = nci_h + NCI_ELEMS;
        convert_kernel<<<2048, 256, 0, stream>>>(
            (const float4*)nci_emb, (const float4*)fma_emb,
            (uint2*)nci_h, (uint2*)fma_h);
        ontomap_kernel_h<<<NBLOCKS, 256, 0, stream>>>(
            pos_n, pos_m, pos_f, nci_h, fma_h, n2f_mat, m2f_mat, out, iters);
    } else {
        ontomap_kernel_f32<<<NBLOCKS, 256, 0, stream>>>(
            pos_n, pos_m, pos_f, nci_emb, fma_emb, n2f_mat, m2f_mat, out, iters);
    }
}